// Round 15
// baseline (147.281 us; speedup 1.0000x reference)
//
#include <hip/hip_runtime.h>

typedef unsigned short u16;
typedef unsigned int u32;
typedef __bf16 bf16x8 __attribute__((ext_vector_type(8)));
typedef float f32x4 __attribute__((ext_vector_type(4)));

__device__ __forceinline__ u16 f2bf(float f) {
  u32 u = __builtin_bit_cast(u32, f);
  u = (u + 0x7FFFu + ((u >> 16) & 1u)) >> 16;
  return (u16)u;
}
__device__ __forceinline__ float bf2f(u16 h) {
  u32 u = ((u32)h) << 16;
  return __builtin_bit_cast(float, u);
}

#define GLD16(gp, lp) __builtin_amdgcn_global_load_lds( \
    (const __attribute__((address_space(1))) u32*)(const void*)(gp), \
    (__attribute__((address_space(3))) u32*)(void*)(lp), 16, 0, 0)
#define SBAR() __builtin_amdgcn_s_barrier()
#define SCHED0() __builtin_amdgcn_sched_barrier(0)

// ---------------------------------------------------------------------------
__global__ __launch_bounds__(256) void cast_both(const float* __restrict__ w_in,
                                                 u16* __restrict__ wq,
                                                 const float* __restrict__ w_out,
                                                 u16* __restrict__ wo) {
  int i = blockIdx.x * 256 + threadIdx.x;
  const float* src = w_in; u16* dst = wq; int idx = i;
  if (i >= 196608) { src = w_out; dst = wo; idx = i - 196608; }
  float4 v = *(const float4*)(src + (size_t)idx * 4);
  ushort4 u;
  u.x = f2bf(v.x); u.y = f2bf(v.y); u.z = f2bf(v.z); u.w = f2bf(v.w);
  *(ushort4*)(dst + (size_t)idx * 4) = u;
}

// ---------------------------------------------------------------------------
// permute_in: x (B,C,64,64,64) fp32 -> xw rows n-major: row = nw*8 + b, col e
__global__ __launch_bounds__(256) void permute_in(const float* __restrict__ x,
                                                  u16* __restrict__ xw) {
  __shared__ float lds[128 * 64];
  int t = threadIdx.x;
  int bx = blockIdx.x;                 // jx*16 + jy
  int b = blockIdx.y;
  int jx = bx >> 4, jy = bx & 15;
#pragma unroll
  for (int it = 0; it < 8; ++it) {
    int idx = t + it * 256;
    int row = idx >> 4, z4 = idx & 15;
    int c = row >> 4, qx = (row >> 2) & 3, qy = row & 3;
    int X = (jx * 4 + qx + 60) & 63;
    int Y = (jy * 4 + qy + 60) & 63;
    float4 v = *(const float4*)(x + ((((size_t)(b * 8 + c) * 64 + X) * 64 + Y) * 64 + z4 * 4));
    *(float4*)(lds + row * 64 + ((z4 ^ (row & 7)) << 2)) = v;
  }
  __syncthreads();
#pragma unroll
  for (int it = 0; it < 8; ++it) {
    int idx = t + it * 256;
    int jz = idx >> 7, r = idx & 127;
    int z4r = (jz + 15) & 15;
    float4 v = *(const float4*)(lds + r * 64 + ((z4r ^ (r & 7)) << 2));
    int nw = jx * 256 + jy * 16 + jz;
    ushort4 u;
    u.x = f2bf(v.x); u.y = f2bf(v.y); u.z = f2bf(v.z); u.w = f2bf(v.w);
    *(ushort4*)(xw + (size_t)(nw * 8 + b) * 512 + r * 4) = u;
  }
}

// ---------------------------------------------------------------------------
// Fused QKV GEMM + attention.
// K-loop: r6's measured-best schedule (78.7us) — BM=256, BN=192 (head h),
// BK=64, 8 waves (2x4), 16x16x32 MFMA, 4-phase K-tile, vmcnt(0) at tile end.
// Epilogue: r12's verified fp32 chunked ctile (8 chunks x 32 rows, XOR
// swizzle, float4 dots) — removes ~3000 VALU/thread of bf16 extract/convert.
__global__ __launch_bounds__(512, 1) void gemm_qkv_attn(const u16* __restrict__ A,
                                                        const u16* __restrict__ W,
                                                        const float* __restrict__ bias,
                                                        u16* __restrict__ O) {
  __shared__ u16 smem[57344];     // 114688 B: As[2][16384] + Bs[2][12288]
  u16* As = smem;
  u16* Bs = smem + 32768;
  float* ctf = (float*)smem;      // [32][204] f32 = 26112 B (epilogue only)

  int cpx = gridDim.x >> 3;       // 1024/8 = 128
  int wg = (blockIdx.x & 7) * cpx + (blockIdx.x >> 3);
  int mb = wg >> 3, h = wg & 7;
  int m0 = mb * 256;

  int tid = threadIdx.x;
  int w = tid >> 6, l = tid & 63;
  int wr = w >> 2, wc = w & 3;
  int lr = l & 15, lg = l >> 4;

  // staging sources (per-lane, pre-swizzled): slot s -> row=s>>3, chunk kg=(s&7)^(row&7)
  const u16* pa[4]; int dA[4];
#pragma unroll
  for (int i = 0; i < 4; ++i) {
    int slot = w * 256 + i * 64 + l;
    int row = slot >> 3, kg = (slot & 7) ^ (row & 7);
    pa[i] = A + (size_t)(m0 + row) * 512 + kg * 8;
    dA[i] = (w * 256 + i * 64) * 8;
  }
  const u16* pb[3]; int dB[3];
#pragma unroll
  for (int i = 0; i < 3; ++i) {
    int slot = w * 192 + i * 64 + l;
    int row = slot >> 3, kg = (slot & 7) ^ (row & 7);
    int grow = (row >> 6) * 512 + h * 64 + (row & 63);
    pb[i] = W + (size_t)grow * 512 + kg * 8;
    dB[i] = (w * 192 + i * 64) * 8;
  }

  int cx0 = lg ^ (lr & 7), cx1 = cx0 ^ 4;
  int aofs[2] = { (wr * 128 + lr) * 64 + cx0 * 8, (wr * 128 + lr) * 64 + cx1 * 8 };
  int bofs[2] = { (wc * 48 + lr) * 64 + cx0 * 8, (wc * 48 + lr) * 64 + cx1 * 8 };

  f32x4 acc[8][3] = {};

  // prologue: stage tile 0
#pragma unroll
  for (int i = 0; i < 4; ++i) GLD16(pa[i], As + dA[i]);
#pragma unroll
  for (int i = 0; i < 3; ++i) GLD16(pb[i], Bs + dB[i]);
  asm volatile("s_waitcnt vmcnt(0)" ::: "memory");
  SCHED0(); SBAR(); SCHED0();

  for (int t = 0; t < 8; ++t) {
    const u16* AsT = As + (t & 1) * 16384;
    const u16* BsT = Bs + (t & 1) * 12288;
    u16* Ad = As + ((t + 1) & 1) * 16384;
    u16* Bd = Bs + ((t + 1) & 1) * 12288;
    int nx = (t + 1) * 64;
    bool st = (t < 7);
    bf16x8 bfr[3][2];
#pragma unroll
    for (int pg = 0; pg < 4; ++pg) {
      bf16x8 afr[2][2];
#pragma unroll
      for (int mi = 0; mi < 2; ++mi)
#pragma unroll
        for (int kk = 0; kk < 2; ++kk)
          afr[mi][kk] = *(const bf16x8*)(AsT + aofs[kk] + (pg * 2 + mi) * 1024);
      if (pg == 0) {
#pragma unroll
        for (int n = 0; n < 3; ++n)
#pragma unroll
          for (int kk = 0; kk < 2; ++kk)
            bfr[n][kk] = *(const bf16x8*)(BsT + bofs[kk] + n * 1024);
      }
      if (pg == 0 && st) { GLD16(pa[0] + nx, Ad + dA[0]); GLD16(pa[1] + nx, Ad + dA[1]); }
      if (pg == 1 && st) { GLD16(pa[2] + nx, Ad + dA[2]); GLD16(pa[3] + nx, Ad + dA[3]); }
      if (pg == 2 && st) { GLD16(pb[0] + nx, Bd + dB[0]); GLD16(pb[1] + nx, Bd + dB[1]); }
      if (pg == 3 && st) { GLD16(pb[2] + nx, Bd + dB[2]); }
      SCHED0();
      __builtin_amdgcn_s_setprio(1);
#pragma unroll
      for (int mi = 0; mi < 2; ++mi)
#pragma unroll
        for (int n = 0; n < 3; ++n)
#pragma unroll
          for (int kk = 0; kk < 2; ++kk)
            acc[pg * 2 + mi][n] =
                __builtin_amdgcn_mfma_f32_16x16x32_bf16(bfr[n][kk], afr[mi][kk],
                                                        acc[pg * 2 + mi][n], 0, 0, 0);
      __builtin_amdgcn_s_setprio(0);
      SCHED0();
    }
    asm volatile("s_waitcnt vmcnt(0)" ::: "memory");
    SCHED0(); SBAR(); SCHED0();
  }

  __syncthreads();   // staging reads drained; ctf may overwrite

  // bias values (chunk-invariant per wc,n,lg)
  float4 bvv[3];
#pragma unroll
  for (int n = 0; n < 3; ++n) {
    int col0 = wc * 48 + n * 16 + lg * 4;
    int gcol = ((col0 >> 6) << 9) + (h << 6) + (col0 & 63);
    bvv[n] = *(const float4*)(bias + gcol);
  }

  // ---- 8 chunks of 32 rows; writers: waves with wr == c>>2 (m = (c&3)*2+mm)
#pragma unroll
  for (int c = 0; c < 8; ++c) {
    if ((c >> 2) == wr) {
#pragma unroll
      for (int mm = 0; mm < 2; ++mm) {
        const int m = (c & 3) * 2 + mm;
        int row_local = mm * 16 + lr;
        int skey = ((row_local >> 3) & 3) << 2;
#pragma unroll
        for (int n = 0; n < 3; ++n) {
          int col0 = wc * 48 + n * 16 + lg * 4;
          float4 stv;
          stv.x = acc[m][n][0] + bvv[n].x;
          stv.y = acc[m][n][1] + bvv[n].y;
          stv.z = acc[m][n][2] + bvv[n].z;
          stv.w = acc[m][n][3] + bvv[n].w;
          *(float4*)(ctf + row_local * 204 + (col0 ^ skey)) = stv;
        }
      }
    }
    __syncthreads();
    if (w < 4) {   // attention: wave w handles window w of this chunk
      int qi = l >> 3, j = l & 7;
      int K4 = w << 2;
      const float* qr = ctf + (w * 8 + qi) * 204;
      const float* kr = ctf + (w * 8 + j) * 204;
      float sc = 0.f;
#pragma unroll
      for (int d = 0; d < 16; ++d) {
        float4 qv = *(const float4*)(qr + ((d * 4) ^ K4));
        float4 kv = *(const float4*)(kr + ((64 + d * 4) ^ K4));
        sc += qv.x * kv.x + qv.y * kv.y + qv.z * kv.z + qv.w * kv.w;
      }
      sc *= 0.125f;
      float mx = sc;
      mx = fmaxf(mx, __shfl_xor(mx, 1));
      mx = fmaxf(mx, __shfl_xor(mx, 2));
      mx = fmaxf(mx, __shfl_xor(mx, 4));
      float p = __expf(sc - mx);
      float sum = p;
      sum += __shfl_xor(sum, 1);
      sum += __shfl_xor(sum, 2);
      sum += __shfl_xor(sum, 4);
      p /= sum;
      float pr[8];
      int lb = l & 56;
#pragma unroll
      for (int jj = 0; jj < 8; ++jj) pr[jj] = __shfl(p, lb + jj);
      float ov[8] = {};
#pragma unroll
      for (int jj = 0; jj < 8; ++jj) {
        const float* vr = ctf + (w * 8 + jj) * 204;
        int b0 = 128 + j * 8;
        float4 va = *(const float4*)(vr + (b0 ^ K4));
        float4 vb = *(const float4*)(vr + ((b0 + 4) ^ K4));
        float pj = pr[jj];
        ov[0] += pj * va.x; ov[1] += pj * va.y; ov[2] += pj * va.z; ov[3] += pj * va.w;
        ov[4] += pj * vb.x; ov[5] += pj * vb.y; ov[6] += pj * vb.z; ov[7] += pj * vb.w;
      }
      ushort4 r0, r1;
      r0.x = f2bf(ov[0]); r0.y = f2bf(ov[1]); r0.z = f2bf(ov[2]); r0.w = f2bf(ov[3]);
      r1.x = f2bf(ov[4]); r1.y = f2bf(ov[5]); r1.z = f2bf(ov[6]); r1.w = f2bf(ov[7]);
      u16* dst = O + (size_t)(m0 + c * 32 + w * 8 + qi) * 512 + h * 64 + j * 8;
      *(ushort4*)dst = r0;
      *(ushort4*)(dst + 4) = r1;
    }
    __syncthreads();
  }
}

// ---------------------------------------------------------------------------
// out-proj GEMM + FUSED reassembly/roll (r14, unchanged): C = o @ wo^T + bias
// written directly as out (B,C,64,64,64) fp32. 256x256 tile, BK=64.
__global__ __launch_bounds__(512, 1) void gemm_out_fused(const u16* __restrict__ A,
                                                         const u16* __restrict__ W,
                                                         const float* __restrict__ bias,
                                                         float* __restrict__ outp) {
  __shared__ u16 smem[65536];     // 131072 B: As[2][16384] + Bs[2][16384]
  u16* As = smem;
  u16* Bs = smem + 32768;
  float* ldsT = (float*)smem;     // [32][260] fp32 (epilogue only)

  int cpx = gridDim.x >> 3;       // 256/8 = 32
  int wg = (blockIdx.x & 7) * cpx + (blockIdx.x >> 3);
  int mb = wg >> 1, nb = wg & 1;
  int m0 = mb * 256, n0 = nb * 256;

  int tid = threadIdx.x;
  int w = tid >> 6, l = tid & 63;
  int wr = w >> 2, wc = w & 3;
  int lr = l & 15, lg = l >> 4;

  const u16* pa[4]; const u16* pb[4]; int dS[4];
#pragma unroll
  for (int i = 0; i < 4; ++i) {
    int slot = w * 256 + i * 64 + l;
    int row = slot >> 3, kg = (slot & 7) ^ (row & 7);
    pa[i] = A + (size_t)(m0 + row) * 512 + kg * 8;
    pb[i] = W + (size_t)(n0 + row) * 512 + kg * 8;
    dS[i] = (w * 256 + i * 64) * 8;
  }

  int cx0 = lg ^ (lr & 7), cx1 = cx0 ^ 4;
  int aofs[2] = { (wr * 128 + lr) * 64 + cx0 * 8, (wr * 128 + lr) * 64 + cx1 * 8 };
  int bofs[2] = { (wc * 64 + lr) * 64 + cx0 * 8, (wc * 64 + lr) * 64 + cx1 * 8 };

  f32x4 acc[8][4] = {};

#pragma unroll
  for (int i = 0; i < 4; ++i) GLD16(pa[i], As + dS[i]);
#pragma unroll
  for (int i = 0; i < 4; ++i) GLD16(pb[i], Bs + dS[i]);
  asm volatile("s_waitcnt vmcnt(0)" ::: "memory");
  SCHED0(); SBAR(); SCHED0();

  for (int t = 0; t < 8; ++t) {
    const u16* AsT = As + (t & 1) * 16384;
    const u16* BsT = Bs + (t & 1) * 16384;
    u16* Ad = As + ((t + 1) & 1) * 16384;
    u16* Bd = Bs + ((t + 1) & 1) * 16384;
    int nx = (t + 1) * 64;
    bool st = (t < 7);
    bf16x8 bfr[4][2];
#pragma unroll
    for (int pg = 0; pg < 4; ++pg) {
      bf16x8 afr[2][2];
#pragma unroll
      for (int mi = 0; mi < 2; ++mi)
#pragma unroll
        for (int kk = 0; kk < 2; ++kk)
          afr[mi][kk] = *(const bf16x8*)(AsT + aofs[kk] + (pg * 2 + mi) * 1024);
      if (pg == 0) {
#pragma unroll
        for (int n = 0; n < 4; ++n)
#pragma unroll
          for (int kk = 0; kk < 2; ++kk)
            bfr[n][kk] = *(const bf16x8*)(BsT + bofs[kk] + n * 1024);
      }
      if (pg == 0 && st) { GLD16(pa[0] + nx, Ad + dS[0]); GLD16(pa[1] + nx, Ad + dS[1]); }
      if (pg == 1 && st) { GLD16(pa[2] + nx, Ad + dS[2]); GLD16(pa[3] + nx, Ad + dS[3]); }
      if (pg == 2 && st) { GLD16(pb[0] + nx, Bd + dS[0]); GLD16(pb[1] + nx, Bd + dS[1]); }
      if (pg == 3 && st) { GLD16(pb[2] + nx, Bd + dS[2]); GLD16(pb[3] + nx, Bd + dS[3]); }
      SCHED0();
      __builtin_amdgcn_s_setprio(1);
#pragma unroll
      for (int mi = 0; mi < 2; ++mi)
#pragma unroll
        for (int n = 0; n < 4; ++n)
#pragma unroll
          for (int kk = 0; kk < 2; ++kk)
            acc[pg * 2 + mi][n] =
                __builtin_amdgcn_mfma_f32_16x16x32_bf16(bfr[n][kk], afr[mi][kk],
                                                        acc[pg * 2 + mi][n], 0, 0, 0);
      __builtin_amdgcn_s_setprio(0);
      SCHED0();
    }
    asm volatile("s_waitcnt vmcnt(0)" ::: "memory");
    SCHED0(); SBAR(); SCHED0();
  }

  __syncthreads();   // staging reads drained before ldsT overwrite

  float4 bvv[4];
#pragma unroll
  for (int n = 0; n < 4; ++n)
    bvv[n] = *(const float4*)(bias + n0 + wc * 64 + n * 16 + lg * 4);

  int ix = mb >> 3;
  int iy0 = (mb * 2) & 15;
  int jhalf = lr >> 3;

#pragma unroll 1
  for (int b = 0; b < 8; ++b) {
    if ((lr & 7) == b) {
#pragma unroll
      for (int m = 0; m < 8; ++m) {
        int j = wr * 16 + m * 2 + jhalf;
#pragma unroll
        for (int n = 0; n < 4; ++n) {
          int col0 = wc * 64 + n * 16 + lg * 4;
          float4 stv;
          stv.x = acc[m][n][0] + bvv[n].x;
          stv.y = acc[m][n][1] + bvv[n].y;
          stv.z = acc[m][n][2] + bvv[n].z;
          stv.w = acc[m][n][3] + bvv[n].w;
          *(float4*)(ldsT + j * 260 + col0) = stv;
        }
      }
    }
    __syncthreads();
#pragma unroll
    for (int it = 0; it < 4; ++it) {
      int idx = tid + it * 512;
      int w4 = idx & 15, iyr = (idx >> 4) & 1, fl = idx >> 5;
      int cl = fl >> 4, px = (fl >> 2) & 3, py = fl & 3;
      int W0 = (w4 * 4 + 4) & 63;
      int pz = W0 >> 4, iz0 = W0 & 15;
      int fa = fl * 4 + pz;
      int rbase = iyr * 16 + iz0;
      float4 v;
      v.x = ldsT[(rbase + 0) * 260 + fa];
      v.y = ldsT[(rbase + 1) * 260 + fa];
      v.z = ldsT[(rbase + 2) * 260 + fa];
      v.w = ldsT[(rbase + 3) * 260 + fa];
      int c = nb * 4 + cl;
      int uu = (px * 16 + ix + 60) & 63;
      int vv = (py * 16 + iy0 + iyr + 60) & 63;
      *(float4*)(outp + ((((size_t)(b * 8 + c) * 64 + uu) * 64 + vv) * 64 + w4 * 4)) = v;
    }
    __syncthreads();
  }
}

// ---------------------------------------------------------------------------
extern "C" void kernel_launch(void* const* d_in, const int* in_sizes, int n_in,
                              void* d_out, int out_size, void* d_ws, size_t ws_size,
                              hipStream_t stream) {
  const float* x     = (const float*)d_in[0];
  const float* w_in  = (const float*)d_in[1];
  const float* b_in  = (const float*)d_in[2];
  const float* w_out = (const float*)d_in[3];
  const float* b_out = (const float*)d_in[4];
  float* out = (float*)d_out;

  char* ws = (char*)d_ws;
  u16* wq  = (u16*)(ws);                      // 1536*512 bf16
  u16* wo  = (u16*)(ws + 1572864);            // 512*512 bf16
  u16* xw2 = (u16*)(ws + 2097152);            // 32768*512 bf16, n-major rows
  u16* o   = (u16*)(ws + 35651584);           // 32768*512 bf16 (attn output)

  cast_both<<<1024, 256, 0, stream>>>(w_in, wq, w_out, wo);
  permute_in<<<dim3(256, 8), 256, 0, stream>>>(x, xw2);
  gemm_qkv_attn<<<1024, 512, 0, stream>>>(xw2, wq, b_in, o);
  gemm_out_fused<<<256, 512, 0, stream>>>(o, wo, b_out, out);
}

// Round 16
// 135.393 us; speedup vs baseline: 1.0878x; 1.0878x over previous
//
#include <hip/hip_runtime.h>

typedef unsigned short u16;
typedef unsigned int u32;
typedef __bf16 bf16x8 __attribute__((ext_vector_type(8)));
typedef float f32x4 __attribute__((ext_vector_type(4)));
typedef unsigned short u16x8 __attribute__((ext_vector_type(8)));

__device__ __forceinline__ u16 f2bf(float f) {
  u32 u = __builtin_bit_cast(u32, f);
  u = (u + 0x7FFFu + ((u >> 16) & 1u)) >> 16;
  return (u16)u;
}
__device__ __forceinline__ float bf2f(u16 h) {
  u32 u = ((u32)h) << 16;
  return __builtin_bit_cast(float, u);
}

#define GLD16(gp, lp) __builtin_amdgcn_global_load_lds( \
    (const __attribute__((address_space(1))) u32*)(const void*)(gp), \
    (__attribute__((address_space(3))) u32*)(void*)(lp), 16, 0, 0)
#define SBAR() __builtin_amdgcn_s_barrier()
#define SCHED0() __builtin_amdgcn_sched_barrier(0)

// ---------------------------------------------------------------------------
__global__ __launch_bounds__(256) void cast_both(const float* __restrict__ w_in,
                                                 u16* __restrict__ wq,
                                                 const float* __restrict__ w_out,
                                                 u16* __restrict__ wo) {
  int i = blockIdx.x * 256 + threadIdx.x;
  const float* src = w_in; u16* dst = wq; int idx = i;
  if (i >= 196608) { src = w_out; dst = wo; idx = i - 196608; }
  float4 v = *(const float4*)(src + (size_t)idx * 4);
  ushort4 u;
  u.x = f2bf(v.x); u.y = f2bf(v.y); u.z = f2bf(v.z); u.w = f2bf(v.w);
  *(ushort4*)(dst + (size_t)idx * 4) = u;
}

// ---------------------------------------------------------------------------
// permute_in: x (B,C,64,64,64) fp32 -> xw rows n-major: row = nw*8 + b, col e
__global__ __launch_bounds__(256) void permute_in(const float* __restrict__ x,
                                                  u16* __restrict__ xw) {
  __shared__ float lds[128 * 64];
  int t = threadIdx.x;
  int bx = blockIdx.x;                 // jx*16 + jy
  int b = blockIdx.y;
  int jx = bx >> 4, jy = bx & 15;
#pragma unroll
  for (int it = 0; it < 8; ++it) {
    int idx = t + it * 256;
    int row = idx >> 4, z4 = idx & 15;
    int c = row >> 4, qx = (row >> 2) & 3, qy = row & 3;
    int X = (jx * 4 + qx + 60) & 63;
    int Y = (jy * 4 + qy + 60) & 63;
    float4 v = *(const float4*)(x + ((((size_t)(b * 8 + c) * 64 + X) * 64 + Y) * 64 + z4 * 4));
    *(float4*)(lds + row * 64 + ((z4 ^ (row & 7)) << 2)) = v;
  }
  __syncthreads();
#pragma unroll
  for (int it = 0; it < 8; ++it) {
    int idx = t + it * 256;
    int jz = idx >> 7, r = idx & 127;
    int z4r = (jz + 15) & 15;
    float4 v = *(const float4*)(lds + r * 64 + ((z4r ^ (r & 7)) << 2));
    int nw = jx * 256 + jy * 16 + jz;
    ushort4 u;
    u.x = f2bf(v.x); u.y = f2bf(v.y); u.z = f2bf(v.z); u.w = f2bf(v.w);
    *(ushort4*)(xw + (size_t)(nw * 8 + b) * 512 + r * 4) = u;
  }
}

// ---------------------------------------------------------------------------
// Fused QKV GEMM + attention — r14 verbatim (measured best: 78.8us).
// BM=256, BN=192 (Q|K|V of head h), BK=64, 8 waves (2x4), 16x16x32 MFMA,
// 4-phase K-tile with staging spread over phases, vmcnt(0) at tile end.
// Epilogue: bf16 ctile, all-512-thread attention (32 win x 16 thr).
__global__ __launch_bounds__(512, 1) void gemm_qkv_attn(const u16* __restrict__ A,
                                                        const u16* __restrict__ W,
                                                        const float* __restrict__ bias,
                                                        u16* __restrict__ O) {
  __shared__ u16 smem[57344];     // 114688 B: As[2][16384] + Bs[2][12288]; ctile aliases
  u16* As = smem;
  u16* Bs = smem + 32768;

  int cpx = gridDim.x >> 3;       // 1024/8 = 128
  int wg = (blockIdx.x & 7) * cpx + (blockIdx.x >> 3);
  int mb = wg >> 3, h = wg & 7;
  int m0 = mb * 256;

  int tid = threadIdx.x;
  int w = tid >> 6, l = tid & 63;
  int wr = w >> 2, wc = w & 3;
  int lr = l & 15, lg = l >> 4;

  const u16* pa[4]; int dA[4];
#pragma unroll
  for (int i = 0; i < 4; ++i) {
    int slot = w * 256 + i * 64 + l;
    int row = slot >> 3, kg = (slot & 7) ^ (row & 7);
    pa[i] = A + (size_t)(m0 + row) * 512 + kg * 8;
    dA[i] = (w * 256 + i * 64) * 8;
  }
  const u16* pb[3]; int dB[3];
#pragma unroll
  for (int i = 0; i < 3; ++i) {
    int slot = w * 192 + i * 64 + l;
    int row = slot >> 3, kg = (slot & 7) ^ (row & 7);
    int grow = (row >> 6) * 512 + h * 64 + (row & 63);
    pb[i] = W + (size_t)grow * 512 + kg * 8;
    dB[i] = (w * 192 + i * 64) * 8;
  }

  int cx0 = lg ^ (lr & 7), cx1 = cx0 ^ 4;
  int aofs[2] = { (wr * 128 + lr) * 64 + cx0 * 8, (wr * 128 + lr) * 64 + cx1 * 8 };
  int bofs[2] = { (wc * 48 + lr) * 64 + cx0 * 8, (wc * 48 + lr) * 64 + cx1 * 8 };

  f32x4 acc[8][3] = {};

#pragma unroll
  for (int i = 0; i < 4; ++i) GLD16(pa[i], As + dA[i]);
#pragma unroll
  for (int i = 0; i < 3; ++i) GLD16(pb[i], Bs + dB[i]);
  asm volatile("s_waitcnt vmcnt(0)" ::: "memory");
  SCHED0(); SBAR(); SCHED0();

  for (int t = 0; t < 8; ++t) {
    const u16* AsT = As + (t & 1) * 16384;
    const u16* BsT = Bs + (t & 1) * 12288;
    u16* Ad = As + ((t + 1) & 1) * 16384;
    u16* Bd = Bs + ((t + 1) & 1) * 12288;
    int nx = (t + 1) * 64;
    bool st = (t < 7);
    bf16x8 bfr[3][2];
#pragma unroll
    for (int pg = 0; pg < 4; ++pg) {
      bf16x8 afr[2][2];
#pragma unroll
      for (int mi = 0; mi < 2; ++mi)
#pragma unroll
        for (int kk = 0; kk < 2; ++kk)
          afr[mi][kk] = *(const bf16x8*)(AsT + aofs[kk] + (pg * 2 + mi) * 1024);
      if (pg == 0) {
#pragma unroll
        for (int n = 0; n < 3; ++n)
#pragma unroll
          for (int kk = 0; kk < 2; ++kk)
            bfr[n][kk] = *(const bf16x8*)(BsT + bofs[kk] + n * 1024);
      }
      if (pg == 0 && st) { GLD16(pa[0] + nx, Ad + dA[0]); GLD16(pa[1] + nx, Ad + dA[1]); }
      if (pg == 1 && st) { GLD16(pa[2] + nx, Ad + dA[2]); GLD16(pa[3] + nx, Ad + dA[3]); }
      if (pg == 2 && st) { GLD16(pb[0] + nx, Bd + dB[0]); GLD16(pb[1] + nx, Bd + dB[1]); }
      if (pg == 3 && st) { GLD16(pb[2] + nx, Bd + dB[2]); }
      SCHED0();
      __builtin_amdgcn_s_setprio(1);
#pragma unroll
      for (int mi = 0; mi < 2; ++mi)
#pragma unroll
        for (int n = 0; n < 3; ++n)
#pragma unroll
          for (int kk = 0; kk < 2; ++kk)
            acc[pg * 2 + mi][n] =
                __builtin_amdgcn_mfma_f32_16x16x32_bf16(bfr[n][kk], afr[mi][kk],
                                                        acc[pg * 2 + mi][n], 0, 0, 0);
      __builtin_amdgcn_s_setprio(0);
      SCHED0();
    }
    asm volatile("s_waitcnt vmcnt(0)" ::: "memory");
    SCHED0(); SBAR(); SCHED0();
  }

  // ---- epilogue: C + bias -> bf16 ctile (aliases staging)
  u16* ct = smem;                 // [256][200] bf16
#pragma unroll
  for (int n = 0; n < 3; ++n) {
    int col0 = wc * 48 + n * 16 + lg * 4;
    int gcol = ((col0 >> 6) << 9) + (h << 6) + (col0 & 63);
    float4 bv = *(const float4*)(bias + gcol);
#pragma unroll
    for (int m = 0; m < 8; ++m) {
      int row = wr * 128 + m * 16 + lr;
      ushort4 uu;
      uu.x = f2bf(acc[m][n][0] + bv.x);
      uu.y = f2bf(acc[m][n][1] + bv.y);
      uu.z = f2bf(acc[m][n][2] + bv.z);
      uu.w = f2bf(acc[m][n][3] + bv.w);
      *(ushort4*)(ct + row * 200 + col0) = uu;
    }
  }
  __syncthreads();

  // ---- attention: 32 windows x 16 threads
  int nw2 = tid >> 4, u4 = tid & 15, qi = u4 >> 1, jh = u4 & 1;
  const u16* qrow = ct + (nw2 * 8 + qi) * 200;
  float s4[4];
#pragma unroll
  for (int jj = 0; jj < 4; ++jj) {
    const u16* kr = ct + (nw2 * 8 + jh * 4 + jj) * 200 + 64;
    float sacc = 0.f;
#pragma unroll
    for (int dc = 0; dc < 8; ++dc) {
      u16x8 qv = *(const u16x8*)(qrow + dc * 8);
      u16x8 kv = *(const u16x8*)(kr + dc * 8);
#pragma unroll
      for (int e = 0; e < 8; ++e)
        sacc += bf2f((u16)qv[e]) * bf2f((u16)kv[e]);
    }
    s4[jj] = sacc * 0.125f;
  }
  float r0 = __shfl_xor(s4[0], 1), r1 = __shfl_xor(s4[1], 1);
  float r2 = __shfl_xor(s4[2], 1), r3 = __shfl_xor(s4[3], 1);
  float sm[8];
  if (jh == 0) {
    sm[0] = s4[0]; sm[1] = s4[1]; sm[2] = s4[2]; sm[3] = s4[3];
    sm[4] = r0; sm[5] = r1; sm[6] = r2; sm[7] = r3;
  } else {
    sm[0] = r0; sm[1] = r1; sm[2] = r2; sm[3] = r3;
    sm[4] = s4[0]; sm[5] = s4[1]; sm[6] = s4[2]; sm[7] = s4[3];
  }
  float mx = sm[0];
#pragma unroll
  for (int j = 1; j < 8; ++j) mx = fmaxf(mx, sm[j]);
  float p[8], psum = 0.f;
#pragma unroll
  for (int j = 0; j < 8; ++j) { p[j] = __expf(sm[j] - mx); psum += p[j]; }
  float inv = 1.f / psum;

  float ov[32];
#pragma unroll
  for (int e = 0; e < 32; ++e) ov[e] = 0.f;
#pragma unroll
  for (int j = 0; j < 8; ++j) {
    const u16* vr = ct + (nw2 * 8 + j) * 200 + 128 + jh * 32;
    float pj = p[j] * inv;
#pragma unroll
    for (int dc = 0; dc < 4; ++dc) {
      u16x8 vv = *(const u16x8*)(vr + dc * 8);
#pragma unroll
      for (int e = 0; e < 8; ++e)
        ov[dc * 8 + e] += pj * bf2f((u16)vv[e]);
    }
  }
  u32 pk[16];
#pragma unroll
  for (int e = 0; e < 16; ++e)
    pk[e] = (u32)f2bf(ov[2 * e]) | ((u32)f2bf(ov[2 * e + 1]) << 16);
  u32* dst = (u32*)(O + (size_t)(m0 + nw2 * 8 + qi) * 512 + h * 64 + jh * 32);
#pragma unroll
  for (int q4 = 0; q4 < 4; ++q4) {
    uint4 vq; vq.x = pk[q4 * 4]; vq.y = pk[q4 * 4 + 1];
    vq.z = pk[q4 * 4 + 2]; vq.w = pk[q4 * 4 + 3];
    *(uint4*)(dst + q4 * 4) = vq;
  }
}

// ---------------------------------------------------------------------------
// out-proj GEMM + FUSED reassembly/roll, BM=128 x BN=256 (grid 512 = 2 rounds
// -> round-1 store drain overlaps round-2 K-loop). BK=64, 8 waves (2x4),
// wave tile 64x64, acc[4][4]. Epilogue: per b, 16-window ldsT[16][260] fp32,
// 1024 gather tasks -> coalesced float4 stores to out (B,C,64,64,64).
__global__ __launch_bounds__(512, 1) void gemm_out_fused(const u16* __restrict__ A,
                                                         const u16* __restrict__ W,
                                                         const float* __restrict__ bias,
                                                         float* __restrict__ outp) {
  __shared__ u16 smem[49152];     // 98304 B: As[2][8192] + Bs[2][16384]
  u16* As = smem;
  u16* Bs = smem + 16384;
  float* ldsT = (float*)smem;     // [16][260] fp32 = 16640 floats (epilogue)

  int cpx = gridDim.x >> 3;       // 512/8 = 64
  int wg = (blockIdx.x & 7) * cpx + (blockIdx.x >> 3);
  int mb = wg >> 1, nb = wg & 1;  // mb in [0,256): 128-row tile; nb: col half
  int m0 = mb * 128, n0 = nb * 256;

  int tid = threadIdx.x;
  int w = tid >> 6, l = tid & 63;
  int wr = w >> 2, wc = w & 3;
  int lr = l & 15, lg = l >> 4;

  // A staging: 1024 slots (128 rows x 8 chunks); wave owns 128 -> 2 GLD
  const u16* pa[2]; int dA[2];
#pragma unroll
  for (int i = 0; i < 2; ++i) {
    int slot = w * 128 + i * 64 + l;
    int row = slot >> 3, kg = (slot & 7) ^ (row & 7);
    pa[i] = A + (size_t)(m0 + row) * 512 + kg * 8;
    dA[i] = (w * 128 + i * 64) * 8;
  }
  // B staging: 2048 slots (256 rows); wave owns 256 -> 4 GLD
  const u16* pb[4]; int dB[4];
#pragma unroll
  for (int i = 0; i < 4; ++i) {
    int slot = w * 256 + i * 64 + l;
    int row = slot >> 3, kg = (slot & 7) ^ (row & 7);
    pb[i] = W + (size_t)(n0 + row) * 512 + kg * 8;
    dB[i] = (w * 256 + i * 64) * 8;
  }

  int cx0 = lg ^ (lr & 7), cx1 = cx0 ^ 4;
  int aofs[2] = { (wr * 64 + lr) * 64 + cx0 * 8, (wr * 64 + lr) * 64 + cx1 * 8 };
  int bofs[2] = { (wc * 64 + lr) * 64 + cx0 * 8, (wc * 64 + lr) * 64 + cx1 * 8 };

  f32x4 acc[4][4] = {};

#pragma unroll
  for (int i = 0; i < 2; ++i) GLD16(pa[i], As + dA[i]);
#pragma unroll
  for (int i = 0; i < 4; ++i) GLD16(pb[i], Bs + dB[i]);
  asm volatile("s_waitcnt vmcnt(0)" ::: "memory");
  SCHED0(); SBAR(); SCHED0();

  for (int t = 0; t < 8; ++t) {
    const u16* AsT = As + (t & 1) * 8192;
    const u16* BsT = Bs + (t & 1) * 16384;
    u16* Ad = As + ((t + 1) & 1) * 8192;
    u16* Bd = Bs + ((t + 1) & 1) * 16384;
    int nx = (t + 1) * 64;
    bool st = (t < 7);
    bf16x8 bfr[4][2];
#pragma unroll
    for (int pg = 0; pg < 4; ++pg) {   // pg = m index
      bf16x8 afr[2];
#pragma unroll
      for (int kk = 0; kk < 2; ++kk)
        afr[kk] = *(const bf16x8*)(AsT + aofs[kk] + pg * 1024);
      if (pg == 0) {
#pragma unroll
        for (int n = 0; n < 4; ++n)
#pragma unroll
          for (int kk = 0; kk < 2; ++kk)
            bfr[n][kk] = *(const bf16x8*)(BsT + bofs[kk] + n * 1024);
      }
      if (pg == 0 && st) { GLD16(pa[0] + nx, Ad + dA[0]); GLD16(pa[1] + nx, Ad + dA[1]); }
      if (pg == 1 && st) { GLD16(pb[0] + nx, Bd + dB[0]); GLD16(pb[1] + nx, Bd + dB[1]); }
      if (pg == 2 && st) { GLD16(pb[2] + nx, Bd + dB[2]); GLD16(pb[3] + nx, Bd + dB[3]); }
      SCHED0();
      __builtin_amdgcn_s_setprio(1);
#pragma unroll
      for (int n = 0; n < 4; ++n)
#pragma unroll
        for (int kk = 0; kk < 2; ++kk)
          acc[pg][n] = __builtin_amdgcn_mfma_f32_16x16x32_bf16(bfr[n][kk], afr[kk],
                                                               acc[pg][n], 0, 0, 0);
      __builtin_amdgcn_s_setprio(0);
      SCHED0();
    }
    asm volatile("s_waitcnt vmcnt(0)" ::: "memory");
    SCHED0(); SBAR(); SCHED0();
  }

  __syncthreads();   // staging reads drained before ldsT overwrite

  float4 bvv[4];
#pragma unroll
  for (int n = 0; n < 4; ++n)
    bvv[n] = *(const float4*)(bias + n0 + wc * 64 + n * 16 + lg * 4);

  int ix = mb >> 4;              // 16 windows per tile = one iz-run
  int iy = mb & 15;
  int jhalf = lr >> 3;           // row>>3 low bit

#pragma unroll 1
  for (int b = 0; b < 8; ++b) {
    if ((lr & 7) == b) {
#pragma unroll
      for (int m = 0; m < 4; ++m) {
        int j = wr * 8 + m * 2 + jhalf;      // window (=iz) within tile
#pragma unroll
        for (int n = 0; n < 4; ++n) {
          int col0 = wc * 64 + n * 16 + lg * 4;
          float4 stv;
          stv.x = acc[m][n][0] + bvv[n].x;
          stv.y = acc[m][n][1] + bvv[n].y;
          stv.z = acc[m][n][2] + bvv[n].z;
          stv.w = acc[m][n][3] + bvv[n].w;
          *(float4*)(ldsT + j * 260 + col0) = stv;
        }
      }
    }
    __syncthreads();
#pragma unroll
    for (int it = 0; it < 2; ++it) {
      int idx = tid + it * 512;              // [0,1024)
      int w4 = idx & 15, fl = idx >> 4;      // fl in [0,64): local f-quad
      int cl = fl >> 4, px = (fl >> 2) & 3, py = fl & 3;
      int W0 = (w4 * 4 + 4) & 63;
      int pz = W0 >> 4, iz0 = W0 & 15;
      int fa = fl * 4 + pz;
      float4 v;
      v.x = ldsT[(iz0 + 0) * 260 + fa];
      v.y = ldsT[(iz0 + 1) * 260 + fa];
      v.z = ldsT[(iz0 + 2) * 260 + fa];
      v.w = ldsT[(iz0 + 3) * 260 + fa];
      int c = nb * 4 + cl;
      int uu = (px * 16 + ix + 60) & 63;
      int vv = (py * 16 + iy + 60) & 63;
      *(float4*)(outp + ((((size_t)(b * 8 + c) * 64 + uu) * 64 + vv) * 64 + w4 * 4)) = v;
    }
    __syncthreads();
  }
}

// ---------------------------------------------------------------------------
extern "C" void kernel_launch(void* const* d_in, const int* in_sizes, int n_in,
                              void* d_out, int out_size, void* d_ws, size_t ws_size,
                              hipStream_t stream) {
  const float* x     = (const float*)d_in[0];
  const float* w_in  = (const float*)d_in[1];
  const float* b_in  = (const float*)d_in[2];
  const float* w_out = (const float*)d_in[3];
  const float* b_out = (const float*)d_in[4];
  float* out = (float*)d_out;

  char* ws = (char*)d_ws;
  u16* wq  = (u16*)(ws);                      // 1536*512 bf16
  u16* wo  = (u16*)(ws + 1572864);            // 512*512 bf16
  u16* xw2 = (u16*)(ws + 2097152);            // 32768*512 bf16, n-major rows
  u16* o   = (u16*)(ws + 35651584);           // 32768*512 bf16 (attn output)

  cast_both<<<1024, 256, 0, stream>>>(w_in, wq, w_out, wo);
  permute_in<<<dim3(256, 8), 256, 0, stream>>>(x, xw2);
  gemm_qkv_attn<<<1024, 512, 0, stream>>>(xw2, wq, b_in, o);
  gemm_out_fused<<<512, 512, 0, stream>>>(o, wo, b_out, out);
}

// Round 17
// 129.876 us; speedup vs baseline: 1.1340x; 1.0425x over previous
//
#include <hip/hip_runtime.h>

typedef unsigned short u16;
typedef unsigned int u32;
typedef __bf16 bf16x8 __attribute__((ext_vector_type(8)));
typedef float f32x4 __attribute__((ext_vector_type(4)));
typedef unsigned short u16x8 __attribute__((ext_vector_type(8)));

__device__ __forceinline__ u16 f2bf(float f) {
  u32 u = __builtin_bit_cast(u32, f);
  u = (u + 0x7FFFu + ((u >> 16) & 1u)) >> 16;
  return (u16)u;
}
__device__ __forceinline__ float bf2f(u16 h) {
  u32 u = ((u32)h) << 16;
  return __builtin_bit_cast(float, u);
}

#define GLD16(gp, lp) __builtin_amdgcn_global_load_lds( \
    (const __attribute__((address_space(1))) u32*)(const void*)(gp), \
    (__attribute__((address_space(3))) u32*)(void*)(lp), 16, 0, 0)
#define SBAR() __builtin_amdgcn_s_barrier()
#define SCHED0() __builtin_amdgcn_sched_barrier(0)

// ---------------------------------------------------------------------------
__global__ __launch_bounds__(256) void cast_both(const float* __restrict__ w_in,
                                                 u16* __restrict__ wq,
                                                 const float* __restrict__ w_out,
                                                 u16* __restrict__ wo) {
  int i = blockIdx.x * 256 + threadIdx.x;
  const float* src = w_in; u16* dst = wq; int idx = i;
  if (i >= 196608) { src = w_out; dst = wo; idx = i - 196608; }
  float4 v = *(const float4*)(src + (size_t)idx * 4);
  ushort4 u;
  u.x = f2bf(v.x); u.y = f2bf(v.y); u.z = f2bf(v.z); u.w = f2bf(v.w);
  *(ushort4*)(dst + (size_t)idx * 4) = u;
}

// ---------------------------------------------------------------------------
// permute_in: x (B,C,64,64,64) fp32 -> xw rows n-major: row = nw*8 + b, col e
__global__ __launch_bounds__(256) void permute_in(const float* __restrict__ x,
                                                  u16* __restrict__ xw) {
  __shared__ float lds[128 * 64];
  int t = threadIdx.x;
  int bx = blockIdx.x;                 // jx*16 + jy
  int b = blockIdx.y;
  int jx = bx >> 4, jy = bx & 15;
#pragma unroll
  for (int it = 0; it < 8; ++it) {
    int idx = t + it * 256;
    int row = idx >> 4, z4 = idx & 15;
    int c = row >> 4, qx = (row >> 2) & 3, qy = row & 3;
    int X = (jx * 4 + qx + 60) & 63;
    int Y = (jy * 4 + qy + 60) & 63;
    float4 v = *(const float4*)(x + ((((size_t)(b * 8 + c) * 64 + X) * 64 + Y) * 64 + z4 * 4));
    *(float4*)(lds + row * 64 + ((z4 ^ (row & 7)) << 2)) = v;
  }
  __syncthreads();
#pragma unroll
  for (int it = 0; it < 8; ++it) {
    int idx = t + it * 256;
    int jz = idx >> 7, r = idx & 127;
    int z4r = (jz + 15) & 15;
    float4 v = *(const float4*)(lds + r * 64 + ((z4r ^ (r & 7)) << 2));
    int nw = jx * 256 + jy * 16 + jz;
    ushort4 u;
    u.x = f2bf(v.x); u.y = f2bf(v.y); u.z = f2bf(v.z); u.w = f2bf(v.w);
    *(ushort4*)(xw + (size_t)(nw * 8 + b) * 512 + r * 4) = u;
  }
}

// ---------------------------------------------------------------------------
// Fused QKV GEMM + attention — r14 math, halved barrier domain.
// BM=128, BN=192 (Q|K|V of head h), BK=64, 4 waves (1x4), wave tile 128x48
// (identical per-wave shape to r14), 16x16x32 MFMA, 4-phase K-tile.
// LDS 81920 B -> EXACTLY 2 blocks/CU: two independent barrier domains per CU
// so one block's vmcnt/barrier drain is hidden by the other (m114 mechanism).
__global__ __launch_bounds__(256, 2) void gemm_qkv_attn(const u16* __restrict__ A,
                                                        const u16* __restrict__ W,
                                                        const float* __restrict__ bias,
                                                        u16* __restrict__ O) {
  __shared__ u16 smem[40960];     // 81920 B: As[2][8192] + Bs[2][12288]; ctile aliases
  u16* As = smem;
  u16* Bs = smem + 16384;

  int cpx = gridDim.x >> 3;       // 2048/8 = 256
  int wg = (blockIdx.x & 7) * cpx + (blockIdx.x >> 3);
  int mb = wg >> 3, h = wg & 7;
  int m0 = mb * 128;

  int tid = threadIdx.x;
  int w = tid >> 6, l = tid & 63;
  int wc = w;                     // 1x4 wave grid: wave = column
  int lr = l & 15, lg = l >> 4;

  // staging sources (pre-swizzled): slot s -> row=s>>3, chunk kg=(s&7)^(row&7)
  const u16* pa[4]; int dA[4];
#pragma unroll
  for (int i = 0; i < 4; ++i) {
    int slot = w * 256 + i * 64 + l;          // 1024 A slots (128 rows x 8)
    int row = slot >> 3, kg = (slot & 7) ^ (row & 7);
    pa[i] = A + (size_t)(m0 + row) * 512 + kg * 8;
    dA[i] = (w * 256 + i * 64) * 8;
  }
  const u16* pb[6]; int dB[6];
#pragma unroll
  for (int i = 0; i < 6; ++i) {
    int slot = w * 384 + i * 64 + l;          // 1536 B slots (192 rows x 8)
    int row = slot >> 3, kg = (slot & 7) ^ (row & 7);
    int grow = (row >> 6) * 512 + h * 64 + (row & 63);
    pb[i] = W + (size_t)grow * 512 + kg * 8;
    dB[i] = (w * 384 + i * 64) * 8;
  }

  int cx0 = lg ^ (lr & 7), cx1 = cx0 ^ 4;
  int aofs[2] = { lr * 64 + cx0 * 8, lr * 64 + cx1 * 8 };              // + m*1024
  int bofs[2] = { (wc * 48 + lr) * 64 + cx0 * 8, (wc * 48 + lr) * 64 + cx1 * 8 };

  f32x4 acc[8][3] = {};

  // prologue: stage tile 0
#pragma unroll
  for (int i = 0; i < 4; ++i) GLD16(pa[i], As + dA[i]);
#pragma unroll
  for (int i = 0; i < 6; ++i) GLD16(pb[i], Bs + dB[i]);
  asm volatile("s_waitcnt vmcnt(0)" ::: "memory");
  SCHED0(); SBAR(); SCHED0();

  for (int t = 0; t < 8; ++t) {
    const u16* AsT = As + (t & 1) * 8192;
    const u16* BsT = Bs + (t & 1) * 12288;
    u16* Ad = As + ((t + 1) & 1) * 8192;
    u16* Bd = Bs + ((t + 1) & 1) * 12288;
    int nx = (t + 1) * 64;
    bool st = (t < 7);
    bf16x8 bfr[3][2];
#pragma unroll
    for (int pg = 0; pg < 4; ++pg) {
      bf16x8 afr[2][2];
#pragma unroll
      for (int mi = 0; mi < 2; ++mi)
#pragma unroll
        for (int kk = 0; kk < 2; ++kk)
          afr[mi][kk] = *(const bf16x8*)(AsT + aofs[kk] + (pg * 2 + mi) * 1024);
      if (pg == 0) {
#pragma unroll
        for (int n = 0; n < 3; ++n)
#pragma unroll
          for (int kk = 0; kk < 2; ++kk)
            bfr[n][kk] = *(const bf16x8*)(BsT + bofs[kk] + n * 1024);
      }
      if (pg == 0 && st) { GLD16(pa[0] + nx, Ad + dA[0]); GLD16(pa[1] + nx, Ad + dA[1]); }
      if (pg == 1 && st) { GLD16(pa[2] + nx, Ad + dA[2]); GLD16(pa[3] + nx, Ad + dA[3]); }
      if (pg == 2 && st) {
        GLD16(pb[0] + nx, Bd + dB[0]); GLD16(pb[1] + nx, Bd + dB[1]);
        GLD16(pb[2] + nx, Bd + dB[2]);
      }
      if (pg == 3 && st) {
        GLD16(pb[3] + nx, Bd + dB[3]); GLD16(pb[4] + nx, Bd + dB[4]);
        GLD16(pb[5] + nx, Bd + dB[5]);
      }
      SCHED0();
      __builtin_amdgcn_s_setprio(1);
#pragma unroll
      for (int mi = 0; mi < 2; ++mi)
#pragma unroll
        for (int n = 0; n < 3; ++n)
#pragma unroll
          for (int kk = 0; kk < 2; ++kk)
            acc[pg * 2 + mi][n] =
                __builtin_amdgcn_mfma_f32_16x16x32_bf16(bfr[n][kk], afr[mi][kk],
                                                        acc[pg * 2 + mi][n], 0, 0, 0);
      __builtin_amdgcn_s_setprio(0);
      SCHED0();
    }
    asm volatile("s_waitcnt vmcnt(0)" ::: "memory");
    SCHED0(); SBAR(); SCHED0();
  }

  // ---- epilogue: C + bias -> bf16 ctile (aliases staging)
  u16* ct = smem;                 // [128][200] bf16 = 51200 B
#pragma unroll
  for (int n = 0; n < 3; ++n) {
    int col0 = wc * 48 + n * 16 + lg * 4;
    int gcol = ((col0 >> 6) << 9) + (h << 6) + (col0 & 63);
    float4 bv = *(const float4*)(bias + gcol);
#pragma unroll
    for (int m = 0; m < 8; ++m) {
      int row = m * 16 + lr;
      ushort4 uu;
      uu.x = f2bf(acc[m][n][0] + bv.x);
      uu.y = f2bf(acc[m][n][1] + bv.y);
      uu.z = f2bf(acc[m][n][2] + bv.z);
      uu.w = f2bf(acc[m][n][3] + bv.w);
      *(ushort4*)(ct + row * 200 + col0) = uu;
    }
  }
  __syncthreads();

  // ---- attention: 16 windows x 16 threads (r14 pattern)
  int nw2 = tid >> 4, u4 = tid & 15, qi = u4 >> 1, jh = u4 & 1;
  const u16* qrow = ct + (nw2 * 8 + qi) * 200;
  float s4[4];
#pragma unroll
  for (int jj = 0; jj < 4; ++jj) {
    const u16* kr = ct + (nw2 * 8 + jh * 4 + jj) * 200 + 64;
    float sacc = 0.f;
#pragma unroll
    for (int dc = 0; dc < 8; ++dc) {
      u16x8 qv = *(const u16x8*)(qrow + dc * 8);
      u16x8 kv = *(const u16x8*)(kr + dc * 8);
#pragma unroll
      for (int e = 0; e < 8; ++e)
        sacc += bf2f((u16)qv[e]) * bf2f((u16)kv[e]);
    }
    s4[jj] = sacc * 0.125f;
  }
  float r0 = __shfl_xor(s4[0], 1), r1 = __shfl_xor(s4[1], 1);
  float r2 = __shfl_xor(s4[2], 1), r3 = __shfl_xor(s4[3], 1);
  float sm[8];
  if (jh == 0) {
    sm[0] = s4[0]; sm[1] = s4[1]; sm[2] = s4[2]; sm[3] = s4[3];
    sm[4] = r0; sm[5] = r1; sm[6] = r2; sm[7] = r3;
  } else {
    sm[0] = r0; sm[1] = r1; sm[2] = r2; sm[3] = r3;
    sm[4] = s4[0]; sm[5] = s4[1]; sm[6] = s4[2]; sm[7] = s4[3];
  }
  float mx = sm[0];
#pragma unroll
  for (int j = 1; j < 8; ++j) mx = fmaxf(mx, sm[j]);
  float p[8], psum = 0.f;
#pragma unroll
  for (int j = 0; j < 8; ++j) { p[j] = __expf(sm[j] - mx); psum += p[j]; }
  float inv = 1.f / psum;

  float ov[32];
#pragma unroll
  for (int e = 0; e < 32; ++e) ov[e] = 0.f;
#pragma unroll
  for (int j = 0; j < 8; ++j) {
    const u16* vr = ct + (nw2 * 8 + j) * 200 + 128 + jh * 32;
    float pj = p[j] * inv;
#pragma unroll
    for (int dc = 0; dc < 4; ++dc) {
      u16x8 vv = *(const u16x8*)(vr + dc * 8);
#pragma unroll
      for (int e = 0; e < 8; ++e)
        ov[dc * 8 + e] += pj * bf2f((u16)vv[e]);
    }
  }
  u32 pk[16];
#pragma unroll
  for (int e = 0; e < 16; ++e)
    pk[e] = (u32)f2bf(ov[2 * e]) | ((u32)f2bf(ov[2 * e + 1]) << 16);
  u32* dst = (u32*)(O + (size_t)(m0 + nw2 * 8 + qi) * 512 + h * 64 + jh * 32);
#pragma unroll
  for (int q4 = 0; q4 < 4; ++q4) {
    uint4 vq; vq.x = pk[q4 * 4]; vq.y = pk[q4 * 4 + 1];
    vq.z = pk[q4 * 4 + 2]; vq.w = pk[q4 * 4 + 3];
    *(uint4*)(dst + q4 * 4) = vq;
  }
}

// ---------------------------------------------------------------------------
// out-proj GEMM + FUSED reassembly/roll — r14 BM=256 version verbatim
// (measured best: r16's BM=128 split regressed).
__global__ __launch_bounds__(512, 1) void gemm_out_fused(const u16* __restrict__ A,
                                                         const u16* __restrict__ W,
                                                         const float* __restrict__ bias,
                                                         float* __restrict__ outp) {
  __shared__ u16 smem[65536];     // 131072 B: As[2][16384] + Bs[2][16384]
  u16* As = smem;
  u16* Bs = smem + 32768;
  float* ldsT = (float*)smem;     // [32][260] fp32 (epilogue only)

  int cpx = gridDim.x >> 3;       // 256/8 = 32
  int wg = (blockIdx.x & 7) * cpx + (blockIdx.x >> 3);
  int mb = wg >> 1, nb = wg & 1;
  int m0 = mb * 256, n0 = nb * 256;

  int tid = threadIdx.x;
  int w = tid >> 6, l = tid & 63;
  int wr = w >> 2, wc = w & 3;
  int lr = l & 15, lg = l >> 4;

  const u16* pa[4]; const u16* pb[4]; int dS[4];
#pragma unroll
  for (int i = 0; i < 4; ++i) {
    int slot = w * 256 + i * 64 + l;
    int row = slot >> 3, kg = (slot & 7) ^ (row & 7);
    pa[i] = A + (size_t)(m0 + row) * 512 + kg * 8;
    pb[i] = W + (size_t)(n0 + row) * 512 + kg * 8;
    dS[i] = (w * 256 + i * 64) * 8;
  }

  int cx0 = lg ^ (lr & 7), cx1 = cx0 ^ 4;
  int aofs[2] = { (wr * 128 + lr) * 64 + cx0 * 8, (wr * 128 + lr) * 64 + cx1 * 8 };
  int bofs[2] = { (wc * 64 + lr) * 64 + cx0 * 8, (wc * 64 + lr) * 64 + cx1 * 8 };

  f32x4 acc[8][4] = {};

#pragma unroll
  for (int i = 0; i < 4; ++i) GLD16(pa[i], As + dS[i]);
#pragma unroll
  for (int i = 0; i < 4; ++i) GLD16(pb[i], Bs + dS[i]);
  asm volatile("s_waitcnt vmcnt(0)" ::: "memory");
  SCHED0(); SBAR(); SCHED0();

  for (int t = 0; t < 8; ++t) {
    const u16* AsT = As + (t & 1) * 16384;
    const u16* BsT = Bs + (t & 1) * 16384;
    u16* Ad = As + ((t + 1) & 1) * 16384;
    u16* Bd = Bs + ((t + 1) & 1) * 16384;
    int nx = (t + 1) * 64;
    bool st = (t < 7);
    bf16x8 bfr[4][2];
#pragma unroll
    for (int pg = 0; pg < 4; ++pg) {
      bf16x8 afr[2][2];
#pragma unroll
      for (int mi = 0; mi < 2; ++mi)
#pragma unroll
        for (int kk = 0; kk < 2; ++kk)
          afr[mi][kk] = *(const bf16x8*)(AsT + aofs[kk] + (pg * 2 + mi) * 1024);
      if (pg == 0) {
#pragma unroll
        for (int n = 0; n < 4; ++n)
#pragma unroll
          for (int kk = 0; kk < 2; ++kk)
            bfr[n][kk] = *(const bf16x8*)(BsT + bofs[kk] + n * 1024);
      }
      if (pg == 0 && st) { GLD16(pa[0] + nx, Ad + dS[0]); GLD16(pa[1] + nx, Ad + dS[1]); }
      if (pg == 1 && st) { GLD16(pa[2] + nx, Ad + dS[2]); GLD16(pa[3] + nx, Ad + dS[3]); }
      if (pg == 2 && st) { GLD16(pb[0] + nx, Bd + dS[0]); GLD16(pb[1] + nx, Bd + dS[1]); }
      if (pg == 3 && st) { GLD16(pb[2] + nx, Bd + dS[2]); GLD16(pb[3] + nx, Bd + dS[3]); }
      SCHED0();
      __builtin_amdgcn_s_setprio(1);
#pragma unroll
      for (int mi = 0; mi < 2; ++mi)
#pragma unroll
        for (int n = 0; n < 4; ++n)
#pragma unroll
          for (int kk = 0; kk < 2; ++kk)
            acc[pg * 2 + mi][n] =
                __builtin_amdgcn_mfma_f32_16x16x32_bf16(bfr[n][kk], afr[mi][kk],
                                                        acc[pg * 2 + mi][n], 0, 0, 0);
      __builtin_amdgcn_s_setprio(0);
      SCHED0();
    }
    asm volatile("s_waitcnt vmcnt(0)" ::: "memory");
    SCHED0(); SBAR(); SCHED0();
  }

  __syncthreads();   // staging reads drained before ldsT overwrite

  float4 bvv[4];
#pragma unroll
  for (int n = 0; n < 4; ++n)
    bvv[n] = *(const float4*)(bias + n0 + wc * 64 + n * 16 + lg * 4);

  int ix = mb >> 3;
  int iy0 = (mb * 2) & 15;
  int jhalf = lr >> 3;

#pragma unroll 1
  for (int b = 0; b < 8; ++b) {
    if ((lr & 7) == b) {
#pragma unroll
      for (int m = 0; m < 8; ++m) {
        int j = wr * 16 + m * 2 + jhalf;
#pragma unroll
        for (int n = 0; n < 4; ++n) {
          int col0 = wc * 64 + n * 16 + lg * 4;
          float4 stv;
          stv.x = acc[m][n][0] + bvv[n].x;
          stv.y = acc[m][n][1] + bvv[n].y;
          stv.z = acc[m][n][2] + bvv[n].z;
          stv.w = acc[m][n][3] + bvv[n].w;
          *(float4*)(ldsT + j * 260 + col0) = stv;
        }
      }
    }
    __syncthreads();
#pragma unroll
    for (int it = 0; it < 4; ++it) {
      int idx = tid + it * 512;
      int w4 = idx & 15, iyr = (idx >> 4) & 1, fl = idx >> 5;
      int cl = fl >> 4, px = (fl >> 2) & 3, py = fl & 3;
      int W0 = (w4 * 4 + 4) & 63;
      int pz = W0 >> 4, iz0 = W0 & 15;
      int fa = fl * 4 + pz;
      int rbase = iyr * 16 + iz0;
      float4 v;
      v.x = ldsT[(rbase + 0) * 260 + fa];
      v.y = ldsT[(rbase + 1) * 260 + fa];
      v.z = ldsT[(rbase + 2) * 260 + fa];
      v.w = ldsT[(rbase + 3) * 260 + fa];
      int c = nb * 4 + cl;
      int uu = (px * 16 + ix + 60) & 63;
      int vv = (py * 16 + iy0 + iyr + 60) & 63;
      *(float4*)(outp + ((((size_t)(b * 8 + c) * 64 + uu) * 64 + vv) * 64 + w4 * 4)) = v;
    }
    __syncthreads();
  }
}

// ---------------------------------------------------------------------------
extern "C" void kernel_launch(void* const* d_in, const int* in_sizes, int n_in,
                              void* d_out, int out_size, void* d_ws, size_t ws_size,
                              hipStream_t stream) {
  const float* x     = (const float*)d_in[0];
  const float* w_in  = (const float*)d_in[1];
  const float* b_in  = (const float*)d_in[2];
  const float* w_out = (const float*)d_in[3];
  const float* b_out = (const float*)d_in[4];
  float* out = (float*)d_out;

  char* ws = (char*)d_ws;
  u16* wq  = (u16*)(ws);                      // 1536*512 bf16
  u16* wo  = (u16*)(ws + 1572864);            // 512*512 bf16
  u16* xw2 = (u16*)(ws + 2097152);            // 32768*512 bf16, n-major rows
  u16* o   = (u16*)(ws + 35651584);           // 32768*512 bf16 (attn output)

  cast_both<<<1024, 256, 0, stream>>>(w_in, wq, w_out, wo);
  permute_in<<<dim3(256, 8), 256, 0, stream>>>(x, xw2);
  gemm_qkv_attn<<<2048, 256, 0, stream>>>(xw2, wq, b_in, o);
  gemm_out_fused<<<256, 512, 0, stream>>>(o, wo, b_out, out);
}